// Round 4
// baseline (226.078 us; speedup 1.0000x reference)
//
#include <hip/hip_runtime.h>
#include <math.h>

#define B 4
#define H 224
#define W 224
#define C 64
#define K 8
#define WC (W*C)        // 14336
#define HWC (H*W*C)     // 3211264

__device__ inline float wave_reduce_min(float v) {
  #pragma unroll
  for (int off = 32; off > 0; off >>= 1)
    v = fminf(v, __shfl_down(v, off, 64));
  return v;
}
__device__ inline float wave_reduce_max(float v) {
  #pragma unroll
  for (int off = 32; off > 0; off >>= 1)
    v = fmaxf(v, __shfl_down(v, off, 64));
  return v;
}

// ---------------- Kernel 0a: per-block partial min/max per sample ----------------
// scratch layout (in d_out, overwritten later by k_main):
//   [0..511] per-block mins, [512..1023] per-block maxs,
//   [1024..1027] xmin per sample, [1028..1031] inv = 1/(max-min+1e-6)
__global__ __launch_bounds__(256) void k_minmax_part(const float* __restrict__ x,
                                                     float* __restrict__ scratch) {
  int s   = blockIdx.x >> 7;      // 128 blocks per sample
  int blk = blockIdx.x & 127;
  const float4* xs = (const float4*)(x + (size_t)s * HWC);
  const int n4 = HWC / 4;         // 802816
  float vmin = INFINITY, vmax = -INFINITY;
  for (int i = blk*256 + threadIdx.x; i < n4; i += 128*256) {
    float4 v = xs[i];
    vmin = fminf(vmin, fminf(fminf(v.x, v.y), fminf(v.z, v.w)));
    vmax = fmaxf(vmax, fmaxf(fmaxf(v.x, v.y), fmaxf(v.z, v.w)));
  }
  __shared__ float smin[4], smax[4];
  float wmin = wave_reduce_min(vmin), wmax = wave_reduce_max(vmax);
  int wave = threadIdx.x >> 6, lane = threadIdx.x & 63;
  if (lane == 0) { smin[wave] = wmin; smax[wave] = wmax; }
  __syncthreads();
  if (threadIdx.x == 0) {
    float m = fminf(fminf(smin[0], smin[1]), fminf(smin[2], smin[3]));
    float M = fmaxf(fmaxf(smax[0], smax[1]), fmaxf(smax[2], smax[3]));
    scratch[blockIdx.x]       = m;
    scratch[512 + blockIdx.x] = M;
  }
}

__global__ __launch_bounds__(128) void k_minmax_final(float* __restrict__ scratch) {
  int s = blockIdx.x;
  float vmin = scratch[s*128 + threadIdx.x];
  float vmax = scratch[512 + s*128 + threadIdx.x];
  __shared__ float smin[2], smax[2];
  float wmin = wave_reduce_min(vmin), wmax = wave_reduce_max(vmax);
  int wave = threadIdx.x >> 6, lane = threadIdx.x & 63;
  if (lane == 0) { smin[wave] = wmin; smax[wave] = wmax; }
  __syncthreads();
  if (threadIdx.x == 0) {
    float m = fminf(smin[0], smin[1]);
    float M = fmaxf(smax[0], smax[1]);
    scratch[1024 + s] = m;
    scratch[1028 + s] = 1.0f / (M - m + 1e-6f);
  }
}

// ---------------- Kernel 1: vertical prefix of normalized x into P ----------------
// One (w,c) column per thread, serial over all 224 h-steps, 16-deep load batches.
// Grid 448 = B * 112 w-tiles of 2; block 128 = 2 waves (w) x 64 lanes (c).
__global__ __launch_bounds__(128) void k_vpfx(const float* __restrict__ x,
                                              const float* __restrict__ scratch,
                                              float* __restrict__ P) {
  int bid = blockIdx.x;
  int b = bid / 112, wt = bid % 112;
  int w = wt * 2 + (threadIdx.x >> 6);
  int c = threadIdx.x & 63;
  float xmin = scratch[1024 + b];
  float inv  = scratch[1028 + b];
  const float* xb = x + __builtin_amdgcn_readfirstlane(b * HWC);
  float*       Pb = P + __builtin_amdgcn_readfirstlane(b * HWC);
  int lbase = w * C + c;          // per-lane 32-bit index
  float acc = 0.f;
  for (int j0 = 0; j0 < H; j0 += 16) {
    float v[16];
    #pragma unroll
    for (int u = 0; u < 16; ++u) v[u] = xb[lbase + (j0 + u) * WC];
    #pragma unroll
    for (int u = 0; u < 16; ++u) {
      acc = fmaf(v[u] - xmin, inv, acc);
      Pb[lbase + (j0 + u) * WC] = acc;
    }
  }
}

// ---------------- Kernel 2: fused box-sums + OLS + BN + histogram + sigmoid ----------------
// Grid 3584 (XCD-swizzled), 128 threads = 2 waves; wave handles a 28-wide w-chunk of one
// (b,h) row, lane = channel. Uniform row bases in SGPRs; per-lane 32-bit offsets; branchless
// edges; loads batched 4 iterations at a time.
__global__ __launch_bounds__(128, 4) void k_main(
    const float* __restrict__ P, const float* __restrict__ x,
    const float* __restrict__ ols, const float* __restrict__ anchors,
    const float* __restrict__ hwidths, const float* __restrict__ bn_gamma,
    const float* __restrict__ bn_beta, const float* __restrict__ bn_mean,
    const float* __restrict__ bn_var, float* __restrict__ out) {
  int xcd  = blockIdx.x & 7;
  int i    = blockIdx.x >> 3;        // [0,448)
  int rg   = xcd * 112 + (i >> 2);   // global row in [0,896)
  int wave = threadIdx.x >> 6, c = threadIdx.x & 63;
  int chunk = (i & 3) * 2 + wave;    // [0,8)
  int b = rg / H, h = rg % H;
  int w0 = chunk * 28;

  // OLS coefficients: alpha = sum_s cs_s * log(measure_s + eps)
  const float LN2 = 0.69314718055994530942f;
  float wg0 = ols[0], wg1 = ols[1], wg2 = ols[2], wg3 = ols[3];
  float l0 = LN2, l1 = 2.f*LN2, l2 = 3.f*LN2, l3 = 4.f*LN2;
  float wsum = wg0 + wg1 + wg2 + wg3;
  float lrbar = (wg0*l0 + wg1*l1 + wg2*l2 + wg3*l3) / wsum;
  float d0 = l0-lrbar, d1 = l1-lrbar, d2 = l2-lrbar, d3 = l3-lrbar;
  float den = wg0*d0*d0 + wg1*d1*d1 + wg2*d2*d2 + wg3*d3*d3;
  float c0 = wg0*d0/den, c1 = wg1*d1/den, c2 = wg2*d2/den, c3 = wg3*d3/den;

  // BN folded: a = alpha*scl + bofs
  float scl  = bn_gamma[c] * rsqrtf(bn_var[c] + 1e-3f);
  float bofs = bn_beta[c] - bn_mean[c] * scl;
  float anc[K], wd[K];
  #pragma unroll
  for (int k = 0; k < K; ++k) { anc[k] = anchors[c*K + k]; wd[k] = hwidths[c*K + k]; }

  // Uniform row bases (SGPR) + per-lane 32-bit index -> saddr global_load form.
  const int hiA[4] = {1, 2, 4, 8};
  const int loA[4] = {0, 1, 3, 7};
  const float* pt[4]; const float* pb[4]; float fb[4];
  int base_b = b * HWC;
  #pragma unroll
  for (int s = 0; s < 4; ++s) {
    int ht = h + hiA[s]; if (ht > H-1) ht = H-1;
    int hb = h - loA[s] - 1;
    int hbc = hb < 0 ? 0 : hb;
    pt[s] = P + __builtin_amdgcn_readfirstlane(base_b + ht * WC);
    pb[s] = P + __builtin_amdgcn_readfirstlane(base_b + hbc * WC);
    fb[s] = hb < 0 ? 0.f : 1.f;
  }
  const float* xrow = x   + __builtin_amdgcn_readfirstlane(base_b + h * WC);
  float*       orow = out + __builtin_amdgcn_readfirstlane(base_b + h * WC);

  // Sliding-window state (all indices compile-time)
  float ring2[2]   = {0,0};
  float ring4[4]   = {0,0,0,0};
  float ring8[8]   = {0,0,0,0,0,0,0,0};
  float ring16[16] = {0,0,0,0,0,0,0,0,0,0,0,0,0,0,0,0};
  float T0 = 0.f, T1 = 0.f, T2 = 0.f, T3 = 0.f;
  float abuf[8] = {0,0,0,0,0,0,0,0};

  // Emits at t in [15,42]; reads through t=42. Chunked 4 iterations: batch loads, then compute.
  for (int t0 = 0; t0 < 48; t0 += 16) {
    #pragma unroll
    for (int g = 0; g < 4; ++g) {
      float lt[4][4], lb[4][4], lx[4];
      #pragma unroll
      for (int j = 0; j < 4; ++j) {
        int t  = t0 + g*4 + j;
        int wr = w0 - 7 + t;
        int wrc = wr < 0 ? 0 : (wr > W-1 ? W-1 : wr);   // uniform scalar clamp
        int off = wrc * C + c;                           // per-lane 32-bit
        #pragma unroll
        for (int s = 0; s < 4; ++s) { lt[j][s] = pt[s][off]; lb[j][s] = pb[s][off]; }
        int ig  = w0 - 15 + t;
        int igc = ig < 0 ? 0 : (ig > W-1 ? W-1 : ig);
        lx[j] = __builtin_nontemporal_load(&xrow[igc * C + c]);
      }
      #pragma unroll
      for (int j = 0; j < 4; ++j) {
        int u = g*4 + j;              // [0,16)
        int t = t0 + u;
        int wr = w0 - 7 + t;
        float fw = (wr >= 0 && wr < W) ? 1.f : 0.f;     // uniform, branchless
        float m0 = fw * fmaf(-fb[0], lb[j][0], lt[j][0]);
        float m1 = fw * fmaf(-fb[1], lb[j][1], lt[j][1]);
        float m2 = fw * fmaf(-fb[2], lb[j][2], lt[j][2]);
        float m3 = fw * fmaf(-fb[3], lb[j][3], lt[j][3]);
        T0 += m0 - ring2[u&1];  ring2[u&1]  = m0;
        T1 += m1 - ring4[u&3];  ring4[u&3]  = m1;
        T2 += m2 - ring8[u&7];  ring8[u&7]  = m2;
        T3 += m3 - ring16[u];   ring16[u]   = m3;
        abuf[(u+7)&7] += c0 * __logf(fmaxf(T0, 0.f) + 1e-6f);
        abuf[(u+6)&7] += c1 * __logf(fmaxf(T1, 0.f) + 1e-6f);
        abuf[(u+4)&7] += c2 * __logf(fmaxf(T2, 0.f) + 1e-6f);
        abuf[u&7]     += c3 * __logf(fmaxf(T3, 0.f) + 1e-6f);
        if (t >= 15 && t <= 42) {     // ig in [w0, w0+27]
          int ig = w0 - 15 + t;
          float alpha = abuf[u&7];
          float a = alpha * scl + bofs;
          float sc = 0.f;
          #pragma unroll
          for (int k = 0; k < K; ++k)
            sc += fmaxf(0.f, 1.f - wd[k]*fabsf(a - anc[k]));
          float sig = 1.f / (1.f + __expf(-sc));
          __builtin_nontemporal_store(lx[j] + sig, &orow[ig*C + c]);
        }
        abuf[u&7] = 0.f;
      }
    }
  }
}

extern "C" void kernel_launch(void* const* d_in, const int* in_sizes, int n_in,
                              void* d_out, int out_size, void* d_ws, size_t ws_size,
                              hipStream_t stream) {
  const float* x        = (const float*)d_in[0];
  const float* ols      = (const float*)d_in[1];
  const float* anchors  = (const float*)d_in[2];
  const float* hwidths  = (const float*)d_in[3];
  const float* bn_gamma = (const float*)d_in[4];
  const float* bn_beta  = (const float*)d_in[5];
  const float* bn_mean  = (const float*)d_in[6];
  const float* bn_var   = (const float*)d_in[7];
  float* out = (float*)d_out;
  float* P   = (float*)d_ws;       // B*H*W*C floats = 51.4 MB
  float* scratch = out;            // d_out doubles as min/max scratch (read only by k_vpfx,
                                   // which completes before k_main overwrites d_out)

  hipLaunchKernelGGL(k_minmax_part,  dim3(512),   dim3(256), 0, stream, x, scratch);
  hipLaunchKernelGGL(k_minmax_final, dim3(4),     dim3(128), 0, stream, scratch);
  hipLaunchKernelGGL(k_vpfx,         dim3(448),   dim3(128), 0, stream, x, scratch, P);
  hipLaunchKernelGGL(k_main,         dim3(B*H*4), dim3(128), 0, stream,
                     P, x, ols, anchors, hwidths, bn_gamma, bn_beta, bn_mean, bn_var, out);
}

// Round 5
// 215.453 us; speedup vs baseline: 1.0493x; 1.0493x over previous
//
#include <hip/hip_runtime.h>
#include <math.h>

#define B 4
#define H 224
#define W 224
#define C 64
#define K 8
#define WC (W*C)        // 14336
#define HWC (H*W*C)     // 3211264

__device__ inline float wave_reduce_min(float v) {
  #pragma unroll
  for (int off = 32; off > 0; off >>= 1)
    v = fminf(v, __shfl_down(v, off, 64));
  return v;
}
__device__ inline float wave_reduce_max(float v) {
  #pragma unroll
  for (int off = 32; off > 0; off >>= 1)
    v = fmaxf(v, __shfl_down(v, off, 64));
  return v;
}

// ---------------- Kernel 0: per-block partial min/max per sample ----------------
// scratch (in d_out, overwritten later by k_main):
//   [0..2047] per-block mins (sample*512 + blk), [2048..4095] per-block maxs
__global__ __launch_bounds__(256) void k_minmax_part(const float* __restrict__ x,
                                                     float* __restrict__ scratch) {
  int s   = blockIdx.x >> 9;      // 512 blocks per sample
  int blk = blockIdx.x & 511;
  const float4* xs = (const float4*)(x + (size_t)s * HWC);
  const int n4 = HWC / 4;         // 802816
  float vmin = INFINITY, vmax = -INFINITY;
  for (int i = blk*256 + threadIdx.x; i < n4; i += 512*256) {
    float4 v = xs[i];
    vmin = fminf(vmin, fminf(fminf(v.x, v.y), fminf(v.z, v.w)));
    vmax = fmaxf(vmax, fmaxf(fmaxf(v.x, v.y), fmaxf(v.z, v.w)));
  }
  __shared__ float smin[4], smax[4];
  float wmin = wave_reduce_min(vmin), wmax = wave_reduce_max(vmax);
  int wave = threadIdx.x >> 6, lane = threadIdx.x & 63;
  if (lane == 0) { smin[wave] = wmin; smax[wave] = wmax; }
  __syncthreads();
  if (threadIdx.x == 0) {
    float m = fminf(fminf(smin[0], smin[1]), fminf(smin[2], smin[3]));
    float M = fmaxf(fmaxf(smax[0], smax[1]), fmaxf(smax[2], smax[3]));
    scratch[blockIdx.x]        = m;
    scratch[2048 + blockIdx.x] = M;
  }
}

// ---------------- Kernel 1: finalize min/max + column prefix sums into P ----------------
// One block per (b,w), 256 threads = 4 h-quarters x 64 channels.
// Preamble: every block redundantly reduces its sample's 512 partial pairs
// (removes the k_minmax_final kernel + one dispatch bubble).
__global__ __launch_bounds__(256) void k_vpfx(const float* __restrict__ x,
                                              const float* __restrict__ scratch,
                                              float* __restrict__ P) {
  int bid = blockIdx.x;           // b*W + w
  int b = bid / W, w = bid % W;
  int q = threadIdx.x >> 6, c = threadIdx.x & 63;

  // --- final min/max reduce (512 partials per sample, 2 per thread) ---
  float vmin = fminf(scratch[b*512 + threadIdx.x], scratch[b*512 + 256 + threadIdx.x] - 0.f);
  float vmax = fmaxf(scratch[2048 + b*512 + threadIdx.x], scratch[2048 + b*512 + 256 + threadIdx.x]);
  __shared__ float smin[4], smax[4];
  float wmin = wave_reduce_min(vmin), wmax = wave_reduce_max(vmax);
  if ((threadIdx.x & 63) == 0) { smin[q] = wmin; smax[q] = wmax; }
  __syncthreads();
  float xmin = fminf(fminf(smin[0], smin[1]), fminf(smin[2], smin[3]));
  float xmax = fmaxf(fmaxf(smax[0], smax[1]), fmaxf(smax[2], smax[3]));
  float inv  = 1.0f / (xmax - xmin + 1e-6f);

  size_t colbase = (size_t)b*HWC + (size_t)w*C + c;
  const int hq = q * 56;
  const float* xp = x + colbase + (size_t)hq * WC;

  // Load entire quarter into registers (56 independent loads -> deep MLP)
  float v[56];
  #pragma unroll
  for (int j = 0; j < 56; ++j) v[j] = xp[(size_t)j * WC];
  float sum = 0.f;
  #pragma unroll
  for (int j = 0; j < 56; ++j) sum += v[j];

  __shared__ float lds[256];
  lds[threadIdx.x] = sum;
  __syncthreads();

  // Offset = sum of earlier quarters (q is wave-uniform)
  float acc = 0.f;
  for (int qq = 0; qq < q; ++qq) acc += lds[qq*64 + c];

  // Prefix within quarter from registers, normalize on the fly
  float* Pp = P + colbase + (size_t)hq * WC;
  #pragma unroll
  for (int j = 0; j < 56; ++j) {
    acc += v[j];
    Pp[(size_t)j * WC] = (acc - (float)(hq + j + 1) * xmin) * inv;
  }
}

// ---------------- Kernel 2: fused box-sums + OLS + BN + histogram + sigmoid ----------------
// R3 version (known 99 us, FETCH 53.6 MB): grid 3584 XCD-swizzled, 128 thr = 2 waves,
// wave = one 28-wide w-chunk of one (b,h) row, lane = channel. No min-waves bound:
// __launch_bounds__(128,4) raised occupancy but broke P's L2 residency (R4 post-mortem).
__global__ __launch_bounds__(128) void k_main(
    const float* __restrict__ P, const float* __restrict__ x,
    const float* __restrict__ ols, const float* __restrict__ anchors,
    const float* __restrict__ hwidths, const float* __restrict__ bn_gamma,
    const float* __restrict__ bn_beta, const float* __restrict__ bn_mean,
    const float* __restrict__ bn_var, float* __restrict__ out) {
  int xcd  = blockIdx.x & 7;
  int i    = blockIdx.x >> 3;        // [0,448)
  int rg   = xcd * 112 + (i >> 2);   // global row in [0,896)
  int wave = threadIdx.x >> 6, c = threadIdx.x & 63;
  int chunk = (i & 3) * 2 + wave;    // [0,8)
  int b = rg / H, h = rg % H;
  int w0 = chunk * 28;

  const float LN2 = 0.69314718055994530942f;
  float wg0 = ols[0], wg1 = ols[1], wg2 = ols[2], wg3 = ols[3];
  float l0 = LN2, l1 = 2.f*LN2, l2 = 3.f*LN2, l3 = 4.f*LN2;
  float wsum = wg0 + wg1 + wg2 + wg3;
  float lrbar = (wg0*l0 + wg1*l1 + wg2*l2 + wg3*l3) / wsum;
  float d0 = l0-lrbar, d1 = l1-lrbar, d2 = l2-lrbar, d3 = l3-lrbar;
  float den = wg0*d0*d0 + wg1*d1*d1 + wg2*d2*d2 + wg3*d3*d3;
  float c0 = wg0*d0/den, c1 = wg1*d1/den, c2 = wg2*d2/den, c3 = wg3*d3/den;

  float scl  = bn_gamma[c] * rsqrtf(bn_var[c] + 1e-3f);
  float bofs = bn_beta[c] - bn_mean[c] * scl;
  float anc[K], wd[K];
  #pragma unroll
  for (int k = 0; k < K; ++k) { anc[k] = anchors[c*K + k]; wd[k] = hwidths[c*K + k]; }

  const int hiA[4] = {1, 2, 4, 8};
  const int loA[4] = {0, 1, 3, 7};
  const float* pt[4]; const float* pb[4]; float fb[4];
  #pragma unroll
  for (int s = 0; s < 4; ++s) {
    int ht = h + hiA[s]; if (ht > H-1) ht = H-1;
    int hb = h - loA[s] - 1;
    int hbc = hb < 0 ? 0 : hb;
    pt[s] = P + (size_t)b*HWC + (size_t)ht*WC + c;
    pb[s] = P + (size_t)b*HWC + (size_t)hbc*WC + c;
    fb[s] = hb < 0 ? 0.f : 1.f;
  }

  const float* xrow = x   + (size_t)b*HWC + (size_t)h*WC + c;
  float*       orow = out + (size_t)b*HWC + (size_t)h*WC + c;

  float ring2[2]   = {0,0};
  float ring4[4]   = {0,0,0,0};
  float ring8[8]   = {0,0,0,0,0,0,0,0};
  float ring16[16] = {0,0,0,0,0,0,0,0,0,0,0,0,0,0,0,0};
  float T0 = 0.f, T1 = 0.f, T2 = 0.f, T3 = 0.f;
  float abuf[8] = {0,0,0,0,0,0,0,0};

  for (int t0 = 0; t0 < 48; t0 += 16) {
    #pragma unroll
    for (int u = 0; u < 16; ++u) {
      int t  = t0 + u;
      int wr = w0 - 7 + t;
      float m0 = 0.f, m1 = 0.f, m2 = 0.f, m3 = 0.f;
      if (wr >= 0 && wr < W) {
        int off = wr * C;
        m0 = pt[0][off] - fb[0]*pb[0][off];
        m1 = pt[1][off] - fb[1]*pb[1][off];
        m2 = pt[2][off] - fb[2]*pb[2][off];
        m3 = pt[3][off] - fb[3]*pb[3][off];
      }
      T0 += m0 - ring2[u&1];  ring2[u&1]  = m0;
      T1 += m1 - ring4[u&3];  ring4[u&3]  = m1;
      T2 += m2 - ring8[u&7];  ring8[u&7]  = m2;
      T3 += m3 - ring16[u];   ring16[u]   = m3;
      abuf[(u+7)&7] += c0 * __logf(fmaxf(T0, 0.f) + 1e-6f);
      abuf[(u+6)&7] += c1 * __logf(fmaxf(T1, 0.f) + 1e-6f);
      abuf[(u+4)&7] += c2 * __logf(fmaxf(T2, 0.f) + 1e-6f);
      abuf[u&7]     += c3 * __logf(fmaxf(T3, 0.f) + 1e-6f);
      int ig = w0 - 15 + t;
      if (t >= 15 && ig <= w0 + 27) {
        float alpha = abuf[u&7];
        float a = alpha * scl + bofs;
        float sc = 0.f;
        #pragma unroll
        for (int k = 0; k < K; ++k)
          sc += fmaxf(0.f, 1.f - wd[k]*fabsf(a - anc[k]));
        float sig = 1.f / (1.f + __expf(-sc));
        float xv = __builtin_nontemporal_load(&xrow[ig*C]);
        __builtin_nontemporal_store(xv + sig, &orow[ig*C]);
      }
      abuf[u&7] = 0.f;
    }
  }
}

extern "C" void kernel_launch(void* const* d_in, const int* in_sizes, int n_in,
                              void* d_out, int out_size, void* d_ws, size_t ws_size,
                              hipStream_t stream) {
  const float* x        = (const float*)d_in[0];
  const float* ols      = (const float*)d_in[1];
  const float* anchors  = (const float*)d_in[2];
  const float* hwidths  = (const float*)d_in[3];
  const float* bn_gamma = (const float*)d_in[4];
  const float* bn_beta  = (const float*)d_in[5];
  const float* bn_mean  = (const float*)d_in[6];
  const float* bn_var   = (const float*)d_in[7];
  float* out = (float*)d_out;
  float* P   = (float*)d_ws;       // B*H*W*C floats = 51.4 MB
  float* scratch = out;            // d_out doubles as min/max scratch (consumed by k_vpfx
                                   // before k_main overwrites d_out)

  hipLaunchKernelGGL(k_minmax_part, dim3(2048),  dim3(256), 0, stream, x, scratch);
  hipLaunchKernelGGL(k_vpfx,        dim3(B*W),   dim3(256), 0, stream, x, scratch, P);
  hipLaunchKernelGGL(k_main,        dim3(B*H*4), dim3(128), 0, stream,
                     P, x, ols, anchors, hwidths, bn_gamma, bn_beta, bn_mean, bn_var, out);
}